// Round 14
// baseline (213.444 us; speedup 1.0000x reference)
//
#include <hip/hip_runtime.h>
#include <math.h>

#define BATCH   16384
#define HD      24      // LSTM hidden size
#define NOUTC   24
#define NHID    16
#define NSTEPS  47
#define NG      96
#define NTG     8       // lanes (j-slot groups) per element
#define JPW     3       // j-slots per group
#define GPW     12      // gates per group
#define EPW     8       // elements per wave (64/NTG)
#define WAVES   4
#define GRP     32      // elements per block
#define THREADS 256     // grid 512 -> 2 blocks/CU, 8 waves/CU, barrier-free steps

__device__ __forceinline__ float fast_sigmoid(float x) {
    float t = __expf(-x);
    return __builtin_amdgcn_rcpf(1.0f + t);
}
__device__ __forceinline__ float fast_tanh(float x) {
    float ax = fabsf(x);
    float t  = __expf(-2.0f * ax);
    float r  = (1.0f - t) * __builtin_amdgcn_rcpf(1.0f + t);
    return copysignf(r, x);
}

__global__ __launch_bounds__(THREADS) void policy_kernel(
    const float* __restrict__ W_ih, const float* __restrict__ W_hh,
    const float* __restrict__ b_ih, const float* __restrict__ b_hh,
    const float* __restrict__ Wl,   const float* __restrict__ bl,
    const float* __restrict__ rnd,  float* __restrict__ out)
{
    __shared__ float sWihB[NG][25];                     // [g][c] + bias folded (gather)
    __shared__ float sBias[NG];                         // b_ih + b_hh (step 0)
    __shared__ __align__(16) float sWhhP[HD][NTG][GPW]; // [k][g][t*3+i] : gate = t*24+3g+i
    __shared__ __align__(16) float sWlP[HD][NTG][4];    // [k][g][i] : logit col n = 3g+i (pad 4)
    __shared__ float sBl[NOUTC];
    __shared__ float sPr[GRP][NSTEPS + 1];
    __shared__ unsigned char sAct8[GRP][NSTEPS + 1];

    const int tid  = threadIdx.x;
    const int lane = tid & 63;
    const int wv   = tid >> 6;
    const int g    = lane >> 3;          // j-slot group 0..7
    const int e8   = lane & 7;           // element within wave
    const int elem = wv * EPW + e8;      // element within block
    const int b    = blockIdx.x * GRP + elem;

    // ---- staging (once per block) ----
    for (int i = tid; i < NG * HD; i += THREADS) {
        int gg = i / HD, k = i % HD;
        float bs = b_ih[gg] + b_hh[gg];
        sWihB[gg][k] = W_ih[i] + bs;
        int t = gg / 24, rem = gg % 24;
        sWhhP[k][rem / 3][t * 3 + rem % 3] = W_hh[i];
    }
    for (int i = tid; i < NOUTC * HD; i += THREADS) {
        int n = i / HD, k = i % HD;
        sWlP[k][n / 3][n % 3] = Wl[i];
    }
    if (tid < NG)    sBias[tid] = b_ih[tid] + b_hh[tid];
    if (tid < NOUTC) sBl[tid]   = bl[tid];
    __syncthreads();                                    // weights visible; ONLY barrier until writeout

    float cst[JPW]  = {0.f, 0.f, 0.f};
    float hloc[JPW] = {0.f, 0.f, 0.f};
    float accN[GPW];                                    // GEMV h-term partials; h0=0 -> exactly 0
    #pragma unroll
    for (int q = 0; q < GPW; ++q) accN[q] = 0.f;
    int actE = 0;

    for (int s = 0; s < NSTEPS; ++s) {
        const float r = rnd[s * BATCH + b];

        // ---- complete gates: acc = GEMV-partial + gather row (bias folded) ----
        float a_[GPW];
        if (s == 0) {
            #pragma unroll
            for (int t = 0; t < 4; ++t)
                #pragma unroll
                for (int i = 0; i < JPW; ++i)
                    a_[t * JPW + i] = accN[t * JPW + i] + sBias[t * 24 + 3 * g + i];
        } else {
            #pragma unroll
            for (int t = 0; t < 4; ++t)
                #pragma unroll
                for (int i = 0; i < JPW; ++i)
                    a_[t * JPW + i] = accN[t * JPW + i] + sWihB[t * 24 + 3 * g + i][actE];
        }

        // ---- LSTM cell for own 3 j's (h stays in registers) ----
        #pragma unroll
        for (int i = 0; i < JPW; ++i) {
            float ig = a_[i], fg = a_[JPW + i], gg_ = a_[2 * JPW + i], og = a_[3 * JPW + i];
            float si = fast_sigmoid(ig);
            float sf = fast_sigmoid(fg);
            float so = fast_sigmoid(og);
            float tg = fast_tanh(gg_);
            float cj = sf * cst[i] + si * tg;
            cst[i] = cj;
            hloc[i] = so * fast_tanh(cj);
        }

        // ---- merged k-loop: logits(s) + gates-GEMV(s+1); h via shfl (no barrier) ----
        float l0 = 0.f, l1 = 0.f, l2 = 0.f;
        #pragma unroll
        for (int q = 0; q < GPW; ++q) accN[q] = 0.f;
        #pragma unroll
        for (int k = 0; k < HD; ++k) {
            float hown = (k % 3 == 0) ? hloc[0] : (k % 3 == 1) ? hloc[1] : hloc[2]; // static idx
            float hk = __shfl(hown, (k / 3) * NTG + e8, 64);     // from owner lane, exact bits
            float4 w0 = *(const float4*)&sWhhP[k][g][0];
            float4 w1 = *(const float4*)&sWhhP[k][g][4];
            float4 w2 = *(const float4*)&sWhhP[k][g][8];
            accN[0]  = fmaf(hk, w0.x, accN[0]);
            accN[1]  = fmaf(hk, w0.y, accN[1]);
            accN[2]  = fmaf(hk, w0.z, accN[2]);
            accN[3]  = fmaf(hk, w0.w, accN[3]);
            accN[4]  = fmaf(hk, w1.x, accN[4]);
            accN[5]  = fmaf(hk, w1.y, accN[5]);
            accN[6]  = fmaf(hk, w1.z, accN[6]);
            accN[7]  = fmaf(hk, w1.w, accN[7]);
            accN[8]  = fmaf(hk, w2.x, accN[8]);
            accN[9]  = fmaf(hk, w2.y, accN[9]);
            accN[10] = fmaf(hk, w2.z, accN[10]);
            accN[11] = fmaf(hk, w2.w, accN[11]);
            float4 lv = *(const float4*)&sWlP[k][g][0];          // .w is pad, unused
            l0 = fmaf(hk, lv.x, l0);
            l1 = fmaf(hk, lv.y, l1);
            l2 = fmaf(hk, lv.z, l2);
        }
        l0 += sBl[3 * g + 0];
        l1 += sBl[3 * g + 1];
        l2 += sBl[3 * g + 2];

        // ---- finish: gather logits via shfl, then R12's exact sequential code ----
        const int  cnt = (s + 1) >> 1;
        const bool odd = (s & 1) != 0;
        float Z = 0.f, cum = 0.f, ea = 0.f, m = -INFINITY, pr;
        int a = 0;
        bool found = false;
        if (odd) {
            float v[NOUTC];
            #pragma unroll
            for (int n = 0; n < NOUTC; ++n) {
                float sv = (n % 3 == 0) ? l0 : (n % 3 == 1) ? l1 : l2;   // static select
                v[n] = __shfl(sv, (n / 3) * NTG + e8, 64);
            }
            #pragma unroll
            for (int n = 0; n < NOUTC; ++n) m = fmaxf(m, (n < cnt) ? v[n] : -INFINITY);
            #pragma unroll
            for (int n = 0; n < NOUTC; ++n) v[n] = (n < cnt) ? __expf(v[n] - m) : 0.f;
            #pragma unroll
            for (int n = 0; n < NOUTC; ++n) Z += v[n];                   // sequential 0..23
            const float rZ = r * Z;
            #pragma unroll
            for (int n = 0; n < NOUTC; ++n) {
                cum += v[n];
                if (!found && cum > rZ) { found = true; a = n; ea = v[n]; }
            }
            if (!found) { a = 0; ea = v[0]; }
            pr = ea / Z;                                                 // IEEE div
        } else {
            float v8[8];
            #pragma unroll
            for (int i = 0; i < 8; ++i) {
                int n = NHID + i;
                float sv = (n % 3 == 0) ? l0 : (n % 3 == 1) ? l1 : l2;
                v8[i] = __shfl(sv, (n / 3) * NTG + e8, 64);
            }
            #pragma unroll
            for (int i = 0; i < 8; ++i) m = fmaxf(m, v8[i]);
            #pragma unroll
            for (int i = 0; i < 8; ++i) v8[i] = __expf(v8[i] - m);
            #pragma unroll
            for (int i = 0; i < 8; ++i) Z += v8[i];                      // sequential 16..23
            const float rZ = r * Z;
            #pragma unroll
            for (int i = 0; i < 8; ++i) {
                cum += v8[i];
                if (!found && cum > rZ) { found = true; a = NHID + i; ea = v8[i]; }
            }
            if (!found) { a = 0; ea = 0.f; }                             // ref: p[0]=0 even steps
            pr = ea / Z;
        }

        if (g == 0) { sPr[elem][s] = pr; sAct8[elem][s] = (unsigned char)a; }
        actE = a;                                       // identical in all 8 lanes of the element
    }

    __syncthreads();
    // ---- coalesced write-out ----
    const int base = blockIdx.x * GRP * NSTEPS;
    for (int i = tid; i < GRP * NSTEPS; i += THREADS) {
        int rr = i / NSTEPS, ss = i - rr * NSTEPS;
        out[base + i]                          = sPr[rr][ss];
        out[(size_t)BATCH * NSTEPS + base + i] = (float)sAct8[rr][ss];
    }
}

extern "C" void kernel_launch(void* const* d_in, const int* in_sizes, int n_in,
                              void* d_out, int out_size, void* d_ws, size_t ws_size,
                              hipStream_t stream) {
    const float* W_ih = (const float*)d_in[0];
    const float* W_hh = (const float*)d_in[1];
    const float* b_ih = (const float*)d_in[2];
    const float* b_hh = (const float*)d_in[3];
    const float* Wl   = (const float*)d_in[4];
    const float* bl   = (const float*)d_in[5];
    const float* rnd  = (const float*)d_in[6];
    float* o = (float*)d_out;

    policy_kernel<<<BATCH / GRP, THREADS, 0, stream>>>(W_ih, W_hh, b_ih, b_hh, Wl, bl, rnd, o);
}

// Round 15
// 163.721 us; speedup vs baseline: 1.3037x; 1.3037x over previous
//
#include <hip/hip_runtime.h>
#include <math.h>

#define BATCH   16384
#define HD      24      // LSTM hidden size
#define NOUTC   24
#define NHID    16
#define NSTEPS  47
#define NG      96
#define GRP     16      // elements per block
#define NTG     12      // thread-groups per element
#define JPW     2       // j-slots per thread-group
#define GPW     8       // gates per thread-group
#define THREADS 192     // NTG * GRP, 3 waves; grid 1024 -> 4 blocks/CU

typedef float v2f __attribute__((ext_vector_type(2)));
union F4 { float4 f; v2f h[2]; };

__device__ __forceinline__ v2f pk_fma(v2f a, v2f b, v2f c) {
    v2f d;
    asm("v_pk_fma_f32 %0, %1, %2, %3" : "=v"(d) : "v"(a), "v"(b), "v"(c));
    return d;  // per-component IEEE fma: bit-identical to 2x fmaf
}

__device__ __forceinline__ float fast_sigmoid(float x) {
    float t = __expf(-x);
    return __builtin_amdgcn_rcpf(1.0f + t);
}
__device__ __forceinline__ float fast_tanh(float x) {
    float ax = fabsf(x);
    float t  = __expf(-2.0f * ax);
    float r  = (1.0f - t) * __builtin_amdgcn_rcpf(1.0f + t);
    return copysignf(r, x);
}

__global__ __launch_bounds__(THREADS) void policy_kernel(
    const float* __restrict__ W_ih, const float* __restrict__ W_hh,
    const float* __restrict__ b_ih, const float* __restrict__ b_hh,
    const float* __restrict__ Wl,   const float* __restrict__ bl,
    const float* __restrict__ rnd,  float* __restrict__ out)
{
    __shared__ float sWihB[NG][25];          // [g][c] + bias folded
    __shared__ float sBias[NG];              // b_ih + b_hh (step 0)
    __shared__ __align__(16) float sWhhP[HD][NTG][GPW];  // [k][w][t*2+i] : gate g = t*24 + w*2 + i
    __shared__ __align__(8)  float sWlP[HD][NTG][JPW];   // [k][w][i] : logit col n = w*2+i
    __shared__ float sBl[NOUTC];
    __shared__ float hh[HD][GRP];            // single h buffer (reads/writes barrier-separated)
    __shared__ float sLt[GRP][28];           // transposed logits exchange
    __shared__ float sPr[GRP][NSTEPS + 2];
    __shared__ unsigned char sAct8[GRP][NSTEPS + 2];

    const int tid   = threadIdx.x;
    const int w     = tid >> 4;              // thread-group 0..11
    const int e     = tid & 15;              // element within group
    const int wvIdx = tid >> 6;              // wave in block 0..2 (owns logit cols [8*wvIdx, 8*wvIdx+8))
    const int b     = blockIdx.x * GRP + e;

    // ---- staging (once per block) ----
    for (int i = tid; i < NG * HD; i += THREADS) {
        int g = i / HD, k = i % HD;
        float bs = b_ih[g] + b_hh[g];
        sWihB[g][k] = W_ih[i] + bs;
        int t = g / 24, rem = g % 24;
        sWhhP[k][rem >> 1][t * JPW + (rem & 1)] = W_hh[i];
    }
    for (int i = tid; i < NOUTC * HD; i += THREADS) {
        int n = i / HD, k = i % HD;
        sWlP[k][n >> 1][n & 1] = Wl[i];
    }
    if (tid < NG)    sBias[tid] = b_ih[tid] + b_hh[tid];
    if (tid < NOUTC) sBl[tid]   = bl[tid];
    for (int i = tid; i < HD * GRP; i += THREADS) (&hh[0][0])[i] = 0.f;
    __syncthreads();

    float cst[JPW] = {0.f, 0.f};
    v2f aN[4];                                // GEMV h-term partials; pairs (t,i=0|1); h0=0 -> exact 0
    #pragma unroll
    for (int q = 0; q < 4; ++q) aN[q] = (v2f){0.f, 0.f};
    int act = 0;

    for (int s = 0; s < NSTEPS; ++s) {
        const float r   = rnd[s * BATCH + b];   // issue early; consumed in finish
        const int   cnt = (s + 1) >> 1;
        const bool  odd = (s & 1) != 0;
        const bool  doLog = odd ? (8 * wvIdx < cnt) : (wvIdx == 2);  // wave-uniform

        // ---- complete gates: acc = GEMV-partial + gather row (bias folded) ----
        float a_[GPW];
        if (s == 0) {
            #pragma unroll
            for (int t = 0; t < 4; ++t) {
                a_[t * JPW + 0] = aN[t].x + sBias[t * 24 + w * JPW + 0];
                a_[t * JPW + 1] = aN[t].y + sBias[t * 24 + w * JPW + 1];
            }
        } else {
            #pragma unroll
            for (int t = 0; t < 4; ++t) {
                a_[t * JPW + 0] = aN[t].x + sWihB[t * 24 + w * JPW + 0][act];
                a_[t * JPW + 1] = aN[t].y + sWihB[t * 24 + w * JPW + 1][act];
            }
        }

        // ---- LSTM cell for own 2 j's ----
        #pragma unroll
        for (int i = 0; i < JPW; ++i) {
            float ig = a_[i], fg = a_[JPW + i], gg = a_[2 * JPW + i], og = a_[3 * JPW + i];
            float si = fast_sigmoid(ig);
            float sf = fast_sigmoid(fg);
            float so = fast_sigmoid(og);
            float tg = fast_tanh(gg);
            float cj = sf * cst[i] + si * tg;
            cst[i] = cj;
            hh[w * JPW + i][e] = so * fast_tanh(cj);
        }
        __syncthreads();   // B: new h visible

        // ---- merged k-loop: logits(s) + gates-GEMV(s+1), packed FMA ----
        v2f aL = (v2f){0.f, 0.f};
        #pragma unroll
        for (int q = 0; q < 4; ++q) aN[q] = (v2f){0.f, 0.f};
        if (doLog) {
            #pragma unroll 4
            for (int k = 0; k < HD; ++k) {
                float hk = hh[k][e];
                v2f hk2; hk2.x = hk; hk2.y = hk;
                F4 u0, u1;
                u0.f = *(const float4*)&sWhhP[k][w][0];
                u1.f = *(const float4*)&sWhhP[k][w][4];
                v2f lv = *(const v2f*)&sWlP[k][w][0];
                aN[0] = pk_fma(hk2, u0.h[0], aN[0]);
                aN[1] = pk_fma(hk2, u0.h[1], aN[1]);
                aN[2] = pk_fma(hk2, u1.h[0], aN[2]);
                aN[3] = pk_fma(hk2, u1.h[1], aN[3]);
                aL    = pk_fma(hk2, lv,      aL);
            }
            sLt[e][w * JPW + 0] = aL.x + sBl[w * JPW + 0];
            sLt[e][w * JPW + 1] = aL.y + sBl[w * JPW + 1];
        } else {
            #pragma unroll 4
            for (int k = 0; k < HD; ++k) {
                float hk = hh[k][e];
                v2f hk2; hk2.x = hk; hk2.y = hk;
                F4 u0, u1;
                u0.f = *(const float4*)&sWhhP[k][w][0];
                u1.f = *(const float4*)&sWhhP[k][w][4];
                aN[0] = pk_fma(hk2, u0.h[0], aN[0]);
                aN[1] = pk_fma(hk2, u0.h[1], aN[1]);
                aN[2] = pk_fma(hk2, u1.h[0], aN[2]);
                aN[3] = pk_fma(hk2, u1.h[1], aN[3]);
            }
            // skipped columns are exactly the masked-out ones at step s;
            // stale sLt entries are selected away in the finish.
        }
        __syncthreads();   // C: logits visible

        // ---- redundant in-register finish (identical to R12) ----
        float v[NOUTC];
        #pragma unroll
        for (int n4 = 0; n4 < 6; ++n4) {
            float4 vv = *(const float4*)&sLt[e][n4 * 4];
            v[n4 * 4 + 0] = vv.x; v[n4 * 4 + 1] = vv.y;
            v[n4 * 4 + 2] = vv.z; v[n4 * 4 + 3] = vv.w;
        }
        float Z = 0.f, cum = 0.f, ea = 0.f, m = -INFINITY;
        int a = 0;
        bool found = false;
        if (odd) {
            #pragma unroll
            for (int n = 0; n < NOUTC; ++n) m = fmaxf(m, (n < cnt) ? v[n] : -INFINITY);
            #pragma unroll
            for (int n = 0; n < NOUTC; ++n) v[n] = (n < cnt) ? __expf(v[n] - m) : 0.f;
            #pragma unroll
            for (int n = 0; n < NOUTC; ++n) Z += v[n];
            const float rZ = r * Z;
            #pragma unroll
            for (int n = 0; n < NOUTC; ++n) {
                cum += v[n];
                if (!found && cum > rZ) { found = true; a = n; ea = v[n]; }
            }
            if (!found) { a = 0; ea = v[0]; }
        } else {
            #pragma unroll
            for (int n = NHID; n < NOUTC; ++n) m = fmaxf(m, v[n]);
            #pragma unroll
            for (int n = NHID; n < NOUTC; ++n) v[n] = __expf(v[n] - m);
            #pragma unroll
            for (int n = NHID; n < NOUTC; ++n) Z += v[n];
            const float rZ = r * Z;
            #pragma unroll
            for (int n = NHID; n < NOUTC; ++n) {
                cum += v[n];
                if (!found && cum > rZ) { found = true; a = n; ea = v[n]; }
            }
            if (!found) { a = 0; ea = 0.f; }    // ref: p[0]=0 on even steps
        }
        float pr = ea / Z;                      // IEEE div, mirrors reference

        if (w == 0) { sPr[e][s] = pr; sAct8[e][s] = (unsigned char)a; }
        act = a;
    }

    __syncthreads();
    // ---- coalesced write-out ----
    const int base = blockIdx.x * GRP * NSTEPS;
    for (int i = tid; i < GRP * NSTEPS; i += THREADS) {
        int rr = i / NSTEPS, ss = i - rr * NSTEPS;
        out[base + i]                          = sPr[rr][ss];
        out[(size_t)BATCH * NSTEPS + base + i] = (float)sAct8[rr][ss];
    }
}

extern "C" void kernel_launch(void* const* d_in, const int* in_sizes, int n_in,
                              void* d_out, int out_size, void* d_ws, size_t ws_size,
                              hipStream_t stream) {
    const float* W_ih = (const float*)d_in[0];
    const float* W_hh = (const float*)d_in[1];
    const float* b_ih = (const float*)d_in[2];
    const float* b_hh = (const float*)d_in[3];
    const float* Wl   = (const float*)d_in[4];
    const float* bl   = (const float*)d_in[5];
    const float* rnd  = (const float*)d_in[6];
    float* o = (float*)d_out;

    policy_kernel<<<BATCH / GRP, THREADS, 0, stream>>>(W_ih, W_hh, b_ih, b_hh, Wl, bl, rnd, o);
}